// Round 12
// baseline (198.860 us; speedup 1.0000x reference)
//
#include <hip/hip_runtime.h>
#include <hip/hip_fp16.h>

// ConvSE3: B=1, N=512, J=48, M=16, MID=128, pairs (di,do) in {0,1}^2.
//   k0 : LN1 stats, mask probe, dInv, self-init, w3T->WT fp16, w2T fp16, h2T ones-row
//   k1 : radial MLP via MFMA -> h2T fp16 [c][edge]
//   k2c: FUSED per-(pair,n): EmT (LDS) x h2T window -> S fragments (REGISTERS) ->
//        Sl (LDS overlay) -> MFMA contraction with WT (L2) -> atomicAdd out.
// R12: S never hits global. R11 showed k2a at the bad-pattern HBM ceiling
// (94 MB/dispatch, WRITE 53.7 MB from 8B-scattered S stores); fusion removes
// ~84 MB of HBM traffic (S write + k2b's S read) and one dispatch.

#define EPSV 1e-5f
constexpr int NN  = 512;
constexpr int JJ  = 48;
constexpr int EE  = NN * JJ;   // 24576 edges

// ---- workspace layout (bytes) -------------------------------------------
constexpr size_t WTOFFS[4] = {0, 33280, 66560, 99840};        // halfs, rows [o][CKP]
constexpr size_t ST_BYTE = 398336;
constexpr size_t DI_BYTE = 398464;
constexpr size_t H2T_BYTE  = 33554432;                        // h2T [c][EE] per pair
constexpr size_t H2T_PAIRB = 7372800;                         // bytes per pair slab
constexpr size_t W2H_BYTE  = 67108864;

typedef _Float16 f16_t;
typedef __attribute__((ext_vector_type(4))) _Float16 v4h;
typedef __attribute__((ext_vector_type(8))) _Float16 v8h;
typedef __attribute__((ext_vector_type(4))) float v4f;

// ---------------------------------------------------------------- k0
__global__ __launch_bounds__(256) void k0_prep(
    const float* __restrict__ w1, const float* __restrict__ b1,
    const void* __restrict__ nmask,
    const float* __restrict__ x0, const float* __restrict__ x1,
    const float* __restrict__ ks0, const float* __restrict__ ks1,
    const float* __restrict__ w2,
    const float* __restrict__ w3_00, const float* __restrict__ b3_00,
    const float* __restrict__ w3_01, const float* __restrict__ b3_01,
    const float* __restrict__ w3_10, const float* __restrict__ b3_10,
    const float* __restrict__ w3_11, const float* __restrict__ b3_11,
    float* __restrict__ dInv, float* __restrict__ out, float* __restrict__ stats,
    _Float16* __restrict__ WT, _Float16* __restrict__ w2h,
    _Float16* __restrict__ h2t0)
{
    const int t = threadIdx.x;
    if (blockIdx.x == 0) {
        const int p = t >> 6, lane = t & 63;
        const float w0 = w1[p*128 + lane],       b0 = b1[p*128 + lane];
        const float w1v = w1[p*128 + 64 + lane], b1v = b1[p*128 + 64 + lane];
        float sw = w0 + w1v, sb = b0 + b1v;
        float sww = w0*w0 + w1v*w1v, swb = w0*b0 + w1v*b1v, sbb = b0*b0 + b1v*b1v;
        for (int off = 32; off > 0; off >>= 1) {
            sw  += __shfl_down(sw, off);  sb  += __shfl_down(sb, off);
            sww += __shfl_down(sww, off); swb += __shfl_down(swb, off);
            sbb += __shfl_down(sbb, off);
        }
        if (lane == 0) {
            const float wbar = sw*(1.f/128.f), bbar = sb*(1.f/128.f);
            stats[p*8+0] = wbar; stats[p*8+1] = bbar;
            stats[p*8+2] = sww*(1.f/128.f) - wbar*wbar;
            stats[p*8+3] = swb*(1.f/128.f) - wbar*bbar;
            stats[p*8+4] = sbb*(1.f/128.f) - bbar*bbar;
        }
        return;
    }
    if (blockIdx.x == 1) {
        __shared__ int flag;
        if (t == 0) flag = 0;
        __syncthreads();
        const int* m32 = (const int*)nmask;
        int bad = 0;
        for (int i = t; i < EE/4; i += 256) if ((unsigned)m32[i] > 1u) bad = 1;
        if (bad) flag = 1;
        __syncthreads();
        const int useU8 = flag;
        if (t == 0) stats[30] = useU8 ? 1.f : 0.f;
        for (int n = t; n < NN; n += 256) {
            float s = 0.f;
            if (useU8) {
                const unsigned char* m8 = (const unsigned char*)nmask;
                for (int j = 0; j < JJ; ++j) s += m8[n*JJ + j] ? 1.f : 0.f;
            } else {
                for (int j = 0; j < JJ; ++j) s += m32[n*JJ + j] ? 1.f : 0.f;
            }
            dInv[n] = 1.f / s;
        }
        return;
    }
    if (blockIdx.x < 130) {              // self-interaction init
        const int gid = (blockIdx.x - 2) * 256 + t;
        const int d = gid & 3, o = (gid >> 2) & 15, n = gid >> 6;
        float acc = 0.f;
        if (d == 0) {
            #pragma unroll
            for (int i = 0; i < 16; ++i) acc += ks0[o*16+i] * x0[n*16+i];
        } else {
            const int u = d - 1;
            #pragma unroll
            for (int i = 0; i < 16; ++i) acc += ks1[o*16+i] * x1[(n*16+i)*3 + u];
        }
        out[gid] = acc;
        return;
    }
    if (blockIdx.x < 908) {              // WT: [o][CKP] fp16, zero-padded tail
        const int gid = (blockIdx.x - 130) * 256 + t;   // [0, 199168)
        if (gid >= 199168) return;
        int p, base;
        if      (gid < 33280)  { p = 0; base = 0; }
        else if (gid < 66560)  { p = 1; base = 33280; }
        else if (gid < 99840)  { p = 2; base = 66560; }
        else                   { p = 3; base = 99840; }
        const int KF = (p == 3) ? 48 : 16;
        const int CK = 129*KF, CKP = CK + 16;
        const int e = gid - base;
        const int o = e / CKP, ck = e - o*CKP;
        float v = 0.f;
        if (ck < CK) {
            const int c = ck / KF, k = ck - c*KF;
            const float* w3 = (p==0) ? w3_00 : (p==1) ? w3_01 : (p==2) ? w3_10 : w3_11;
            const float* b3 = (p==0) ? b3_00 : (p==1) ? b3_01 : (p==2) ? b3_10 : b3_11;
            v = (c < 128) ? w3[(size_t)c*(16*KF) + o*KF + k] : b3[o*KF + k];
        }
        WT[base + (size_t)o*CKP + ck] = (_Float16)v;
        return;
    }
    if (blockIdx.x < 1164) {
        // w2 transpose -> fp16: w2h[p][c][k] = w2[p][k][c]
        const int gid = (blockIdx.x - 908) * 256 + t;   // [0, 65536)
        const int p = gid >> 14, rem = gid & 16383;
        const int c = rem >> 7, k = rem & 127;
        w2h[gid] = (_Float16)w2[p*16384 + k*128 + c];
        return;
    }
    // h2T ones row (c=128, the b3 row) per pair
    const int gid = (blockIdx.x - 1164) * 256 + t;      // [0, 12288)
    const int p = gid / 3072, r8 = gid - p*3072;
    union { float4 f; _Float16 h[8]; } one;
    #pragma unroll
    for (int i = 0; i < 8; ++i) one.h[i] = (_Float16)1.f;
    *(float4*)(h2t0 + (size_t)p*(H2T_PAIRB/2) + (size_t)128*EE + r8*8) = one.f;
}

// ---------------------------------------------------------------- k1: radial MLP (MFMA) -> h2T
__global__ __launch_bounds__(256) void k1_mfma(
    const float* __restrict__ rel,
    const float* __restrict__ w1, const float* __restrict__ b1,
    const float* __restrict__ g1, const float* __restrict__ be1,
    const float* __restrict__ b2, const float* __restrict__ g2,
    const float* __restrict__ be2,
    const float* __restrict__ stats, char* __restrict__ ws)
{
    const int p  = blockIdx.y;
    const int e0 = blockIdx.x * 64;
    const int t  = threadIdx.x;
    const _Float16* __restrict__ w2h = (const _Float16*)(ws + W2H_BYTE) + (size_t)p*16384;
    _Float16* __restrict__ h2Tg = (_Float16*)(ws + H2T_BYTE + (size_t)p*H2T_PAIRB);

    __shared__ __align__(16) _Float16 w2L[128*136];
    __shared__ float pb[384];
    _Float16* h1T = w2L;                              // overlay after MFMA

    if (t < 128) {
        pb[t]       = b2[p*128 + t];
        pb[128 + t] = g2[p*128 + t];
        pb[256 + t] = be2[p*128 + t];
    }
    for (int i = t; i < 2048; i += 256) {
        const int c = i >> 4, off = (i & 15) * 8;
        *(float4*)(w2L + c*136 + off) = *(const float4*)(w2h + c*128 + off);
    }

    const int l = t & 63, wv = t >> 6;
    const int q = l >> 4, c16 = l & 15;
    const int m0 = wv * 16;

    const float d    = rel[e0 + m0 + c16];
    const float wbar = stats[p*8+0], bbar = stats[p*8+1];
    const float Cw = stats[p*8+2], Cwb = stats[p*8+3], Cb = stats[p*8+4];
    const float mu1 = fmaf(d, wbar, bbar);
    const float rs1 = rsqrtf(fmaf(d*d, Cw, fmaf(2.f*d, Cwb, Cb)) + EPSV);

    __syncthreads();

    v4f acc[8];
    #pragma unroll
    for (int nt = 0; nt < 8; ++nt) { acc[nt][0]=0.f; acc[nt][1]=0.f; acc[nt][2]=0.f; acc[nt][3]=0.f; }

    #pragma unroll
    for (int ks = 0; ks < 4; ++ks) {
        const int cb = p*128 + ks*32 + q*8;
        const float4 wA = *(const float4*)(w1 + cb),  wB = *(const float4*)(w1 + cb + 4);
        const float4 bA = *(const float4*)(b1 + cb),  bB = *(const float4*)(b1 + cb + 4);
        const float4 gA = *(const float4*)(g1 + cb),  gB = *(const float4*)(g1 + cb + 4);
        const float4 eA = *(const float4*)(be1 + cb), eB = *(const float4*)(be1 + cb + 4);
        const float wv8[8] = {wA.x,wA.y,wA.z,wA.w,wB.x,wB.y,wB.z,wB.w};
        const float bv8[8] = {bA.x,bA.y,bA.z,bA.w,bB.x,bB.y,bB.z,bB.w};
        const float gv8[8] = {gA.x,gA.y,gA.z,gA.w,gB.x,gB.y,gB.z,gB.w};
        const float ev8[8] = {eA.x,eA.y,eA.z,eA.w,eB.x,eB.y,eB.z,eB.w};
        v8h a;
        #pragma unroll
        for (int j = 0; j < 8; ++j) {
            const float y = fmaf((fmaf(d, wv8[j], bv8[j]) - mu1) * rs1, gv8[j], ev8[j]);
            a[j] = (_Float16)fmaxf(y, 0.f);
        }
        const int k0 = ks*32 + q*8;
        #pragma unroll
        for (int nt = 0; nt < 8; ++nt) {
            const v8h bf = *(const v8h*)(w2L + (nt*16 + c16)*136 + k0);
            acc[nt] = __builtin_amdgcn_mfma_f32_16x16x32_f16(a, bf, acc[nt], 0, 0, 0);
        }
    }
    __syncthreads();

    float bl[8], gl[8], bel[8];
    #pragma unroll
    for (int nt = 0; nt < 8; ++nt) {
        bl[nt]  = pb[nt*16 + c16];
        gl[nt]  = pb[128 + nt*16 + c16];
        bel[nt] = pb[256 + nt*16 + c16];
    }
    #pragma unroll
    for (int nt = 0; nt < 8; ++nt)
        #pragma unroll
        for (int r = 0; r < 4; ++r) acc[nt][r] += bl[nt];

    float muR[4], rsR[4];
    #pragma unroll
    for (int r = 0; r < 4; ++r) {
        float s = 0.f, qq = 0.f;
        #pragma unroll
        for (int nt = 0; nt < 8; ++nt) { const float v = acc[nt][r]; s += v; qq += v*v; }
        #pragma unroll
        for (int m = 1; m < 16; m <<= 1) { s += __shfl_xor(s, m); qq += __shfl_xor(qq, m); }
        muR[r] = s * (1.f/128.f);
        rsR[r] = rsqrtf(qq*(1.f/128.f) - muR[r]*muR[r] + EPSV);
    }
    #pragma unroll
    for (int nt = 0; nt < 8; ++nt) {
        union { uint2 uu; _Float16 h[4]; } pk;
        #pragma unroll
        for (int r = 0; r < 4; ++r)
            pk.h[r] = (_Float16)fmaxf(fmaf((acc[nt][r] - muR[r])*rsR[r], gl[nt], bel[nt]), 0.f);
        *(uint2*)(h1T + (nt*16 + c16)*72 + m0 + q*4) = pk.uu;
    }
    __syncthreads();

    for (int i = t; i < 1024; i += 256) {
        const int c = i >> 3, off = (i & 7) * 8;
        *(float4*)(h2Tg + (size_t)c*EE + e0 + off) = *(const float4*)(h1T + c*72 + off);
    }
}

// ---------------------------------------------------------------- k2c: fused Em->S(frags)->w3 contraction
template<int DI, int DO>
__device__ __forceinline__ void k2c_dev(
    const int n, const float* __restrict__ xsrc,
    const int* __restrict__ nidx, const void* __restrict__ nmaskv,
    const float* __restrict__ basis, const _Float16* __restrict__ h2Tg,
    const float* __restrict__ stats, const _Float16* __restrict__ wt,
    const float* __restrict__ dInv, float* __restrict__ out, char* smem)
{
    constexpr int V  = 2*DI + 1;
    constexpr int U  = 2*DO + 1;
    constexpr int F  = 2*(DI < DO ? DI : DO) + 1;
    constexpr int KF = 16*F;
    constexpr int Q  = 16*U*F;
    constexpr int BP = U*V*F;
    constexpr int XW = 16*V;
    constexpr int CK  = 129*KF;
    constexpr int CKP = CK + 16;        // WT row stride (halfs)
    constexpr int SLP = CKP + 8;        // Sl row stride (bank de-alias)
    constexpr int NK  = CKP/32;
    constexpr int MT = Q/16;
    constexpr int NT = 9;
    constexpr int NTILE = MT*NT;
    constexpr int TT = (NTILE + 3)/4;

    _Float16* EmT = (_Float16*)smem;                          // [Q][56]
    char* region2 = smem + Q*112;                             // 16128 B
    float* xg   = (float*)region2;                            // [48][XW]
    float* basL = xg + 48*XW;
    _Float16* h2L = (_Float16*)region2;                       // overlay [144][56]
    int2*  lut  = (int2*)(region2 + 16128);
    int*   idxL = (int*)(lut + Q);
    float* mjf  = (float*)(idxL + 48);
    _Float16* Sl = (_Float16*)smem;                           // phase-C overlay [4][SLP]
    float* red   = (float*)smem;                              // final overlay [4][16][16]

    const int t = threadIdx.x;
    const int wv = t >> 6, l = t & 63;
    const int q8 = l >> 4, l15 = l & 15;

    // h2T window prefetch -> registers: 129 rows x 6 segs x 8 halfs (uint4)
    uint4 h2r[4];
    int   h2i[4];
    #pragma unroll
    for (int uu = 0; uu < 4; ++uu) {
        const int idx = t + uu*256;
        h2i[uu] = (idx < 774) ? idx : -1;
        if (idx < 774) {
            const int r = idx / 6, s = idx - r*6;
            h2r[uu] = *(const uint4*)(h2Tg + (size_t)r*EE + n*48 + s*8);
        }
    }

    if (t < 48) {
        idxL[t] = nidx[n*JJ + t];
        const int useU8 = (stats[30] != 0.f);
        const int mv = useU8 ? (int)((const unsigned char*)nmaskv)[n*JJ + t]
                             : ((const int*)nmaskv)[n*JJ + t];
        mjf[t] = mv ? 1.f : 0.f;
    }
    if (t >= 64 && t < 64 + Q) {
        const int q2 = t - 64;
        const int u = q2 / KF, k = q2 - u*KF, i = k / F, f = k - i*F;
        lut[q2] = make_int2((u*V)*F + f, i*V);
    }
    __syncthreads();

    for (int e = t; e < 48*XW; e += 256) {
        const int j = e / XW, r = e - j*XW;
        xg[e] = xsrc[idxL[j]*XW + r];
    }
    for (int e = t; e < 48*BP; e += 256)
        basL[e] = basis[(size_t)n*48*BP + e];
    __syncthreads();

    // EmT[q][j] = mjf[j] * sum_v basis[j][(u*V+v)*F+f] * xg[j][i*V+v]
    for (int e = t; e < Q*48; e += 256) {
        const int q2 = e / 48, j = e - q2*48;
        const int2 lu = lut[q2];
        float a = 0.f;
        #pragma unroll
        for (int v = 0; v < V; ++v)
            a = fmaf(basL[j*BP + lu.x + v*F], xg[j*XW + lu.y + v], a);
        EmT[q2*56 + j] = (_Float16)(mjf[j] * a);
    }
    __syncthreads();   // xg/basL dead

    // spill h2 window -> h2L
    #pragma unroll
    for (int uu = 0; uu < 4; ++uu) {
        if (h2i[uu] >= 0) {
            const int r = h2i[uu] / 6, s = h2i[uu] - r*6;
            *(uint4*)(h2L + r*56 + s*8) = h2r[uu];
        }
    }
    for (int i = t; i < 15*7; i += 256) {
        const int r = 129 + i/7, s = i - (i/7)*7;
        *(uint4*)(h2L + r*56 + s*8) = make_uint4(0u,0u,0u,0u);
    }
    __syncthreads();

    // phase B: S fragments in registers. D[q][c] = sum_j EmT[q][j]*h2L[c][j]
    v4f dreg[TT];
    #pragma unroll
    for (int i = 0; i < TT; ++i) {
        const int tt = wv + i*4;
        v4f acc; acc[0]=0.f; acc[1]=0.f; acc[2]=0.f; acc[3]=0.f;
        if (tt < NTILE) {
            const int mt = tt / NT, nt = tt - mt*NT;
            #pragma unroll
            for (int ks = 0; ks < 3; ++ks) {
                const v4h a = *(const v4h*)(EmT + (mt*16 + l15)*56 + ks*16 + q8*4);
                const v4h b = *(const v4h*)(h2L + (nt*16 + l15)*56 + ks*16 + q8*4);
                acc = __builtin_amdgcn_mfma_f32_16x16x16f16(a, b, acc, 0, 0, 0);
            }
        }
        dreg[i] = acc;
    }
    __syncthreads();   // EmT/h2L dead

    // zero Sl [4][SLP], then store fragments: Sl[u][c*KF+k]
    for (int i = t; i < (4*SLP*2)/16; i += 256)
        ((uint4*)Sl)[i] = make_uint4(0u,0u,0u,0u);
    __syncthreads();
    #pragma unroll
    for (int i = 0; i < TT; ++i) {
        const int tt = wv + i*4;
        if (tt < NTILE) {
            const int mt = tt / NT, nt = tt - mt*NT;
            const int c = nt*16 + l15;
            if (c <= 128) {
                const int q0 = mt*16 + q8*4;
                const int u = q0 / KF, k0 = q0 - u*KF;
                union { uint2 uu; _Float16 h[4]; } pk;
                #pragma unroll
                for (int r = 0; r < 4; ++r) pk.h[r] = (_Float16)dreg[i][r];
                *(uint2*)(Sl + u*SLP + c*KF + k0) = pk.uu;
            }
        }
    }
    __syncthreads();

    // phase C: D2[o][u] = sum_ck WT[o][ck] * Sl[u][ck], K-split over waves
    constexpr int KC = (NK + 3)/4;
    const int k_lo = wv * KC;
    const int k_hi = (k_lo + KC < NK) ? (k_lo + KC) : NK;
    const _Float16* wrow = wt + (size_t)l15*CKP;
    const _Float16* srow = Sl + (l15 & 3)*SLP;
    v4f acc2; acc2[0]=0.f; acc2[1]=0.f; acc2[2]=0.f; acc2[3]=0.f;
    #pragma unroll 4
    for (int ks = k_lo; ks < k_hi; ++ks) {
        const v8h a = *(const v8h*)(wrow + ks*32 + q8*8);
        const v8h b = *(const v8h*)(srow + ks*32 + q8*8);
        acc2 = __builtin_amdgcn_mfma_f32_16x16x32_f16(a, b, acc2, 0, 0, 0);
    }
    __syncthreads();   // Sl reads done; red overlay safe

    #pragma unroll
    for (int r = 0; r < 4; ++r)
        red[(wv*16 + q8*4 + r)*16 + l15] = acc2[r];   // red[wv][o][u]
    __syncthreads();

    if (t < 16*U) {
        const int o = t & 15, u = t >> 4;
        const float v = red[(0*16 + o)*16 + u] + red[(1*16 + o)*16 + u]
                      + red[(2*16 + o)*16 + u] + red[(3*16 + o)*16 + u];
        atomicAdd(out + (size_t)(n*16 + o)*4 + (DO ? 1 + u : 0), v * dInv[n]);
    }
}

__global__ __launch_bounds__(256, 3) void k2c_all(
    const float* __restrict__ x0, const float* __restrict__ x1,
    const int* __restrict__ nidx, const void* __restrict__ nmask,
    const float* __restrict__ b00, const float* __restrict__ b01,
    const float* __restrict__ b10, const float* __restrict__ b11,
    const float* __restrict__ stats, const float* __restrict__ dInv,
    char* __restrict__ ws, float* __restrict__ out)
{
    __shared__ __align__(16) char smem[49728];   // pair3: max(phaseAB 33.8K, Sl 4*6216*2)
    const int pair = blockIdx.x >> 9, n = blockIdx.x & 511;
    const char* h2t = ws + H2T_BYTE;
    const _Float16* WT = (const _Float16*)ws;
    switch (pair) {
    case 0: k2c_dev<0,0>(n, x0, nidx, nmask, b00, (const _Float16*)(h2t + 0*H2T_PAIRB), stats, WT + WTOFFS[0], dInv, out, smem); break;
    case 1: k2c_dev<0,1>(n, x0, nidx, nmask, b01, (const _Float16*)(h2t + 1*H2T_PAIRB), stats, WT + WTOFFS[1], dInv, out, smem); break;
    case 2: k2c_dev<1,0>(n, x1, nidx, nmask, b10, (const _Float16*)(h2t + 2*H2T_PAIRB), stats, WT + WTOFFS[2], dInv, out, smem); break;
    default: k2c_dev<1,1>(n, x1, nidx, nmask, b11, (const _Float16*)(h2t + 3*H2T_PAIRB), stats, WT + WTOFFS[3], dInv, out, smem); break;
    }
}

// ---------------------------------------------------------------- launch
extern "C" void kernel_launch(void* const* d_in, const int* in_sizes, int n_in,
                              void* d_out, int out_size, void* d_ws, size_t ws_size,
                              hipStream_t stream)
{
    const float* x0    = (const float*)d_in[0];
    const float* x1    = (const float*)d_in[1];
    const float* rel   = (const float*)d_in[2];
    const int*   nidx  = (const int*)d_in[3];
    const void*  nmask = d_in[4];
    const float* basis[4] = {(const float*)d_in[5], (const float*)d_in[6],
                             (const float*)d_in[7], (const float*)d_in[8]};
    const float* w1  = (const float*)d_in[9];
    const float* b1  = (const float*)d_in[10];
    const float* g1  = (const float*)d_in[11];
    const float* be1 = (const float*)d_in[12];
    const float* w2  = (const float*)d_in[13];
    const float* b2  = (const float*)d_in[14];
    const float* g2  = (const float*)d_in[15];
    const float* be2 = (const float*)d_in[16];
    const float* w3a[4] = {(const float*)d_in[17], (const float*)d_in[19],
                           (const float*)d_in[21], (const float*)d_in[23]};
    const float* b3a[4] = {(const float*)d_in[18], (const float*)d_in[20],
                           (const float*)d_in[22], (const float*)d_in[24]};
    const float* ks0 = (const float*)d_in[25];
    const float* ks1 = (const float*)d_in[26];
    float* out = (float*)d_out;

    char*      ws    = (char*)d_ws;
    _Float16*  WT    = (_Float16*)ws;
    float*     stats = (float*)(ws + ST_BYTE);
    float*     dInv  = (float*)(ws + DI_BYTE);
    _Float16*  w2h   = (_Float16*)(ws + W2H_BYTE);
    _Float16*  h2t0  = (_Float16*)(ws + H2T_BYTE);

    k0_prep<<<1212, 256, 0, stream>>>(w1, b1, nmask, x0, x1, ks0, ks1, w2,
                                      w3a[0], b3a[0], w3a[1], b3a[1],
                                      w3a[2], b3a[2], w3a[3], b3a[3],
                                      dInv, out, stats, WT, w2h, h2t0);

    k1_mfma<<<dim3(384, 4), 256, 0, stream>>>(rel, w1, b1, g1, be1, b2, g2, be2, stats, ws);

    k2c_all<<<2048, 256, 0, stream>>>(x0, x1, nidx, nmask,
                                      basis[0], basis[1], basis[2], basis[3],
                                      stats, dInv, ws, out);
}

// Round 13
// 195.692 us; speedup vs baseline: 1.0162x; 1.0162x over previous
//
#include <hip/hip_runtime.h>
#include <hip/hip_fp16.h>

// ConvSE3: B=1, N=512, J=48, M=16, MID=128, pairs (di,do) in {0,1}^2.
//   k0 : LN1 stats, mask probe, dInv, self-init, w3T->WT fp16, w2T fp16, h2T ones-row
//   k1 : radial MLP via MFMA -> h2T fp16 [c][edge]
//   k2c: FUSED per-(pair,n), CHUNKED over c (3 c-tiles/chunk): EmT x h2L -> S frags
//        (<=7 v4f, no spill) -> Sl chunk (LDS) -> partial MFMA contraction w/ WT.
// R13: R12's dreg[21] (84 VGPR) spilled to scratch (WRITE_SIZE 22.7MB of pure
// scratch traffic). Chunking bounds live fragments at 7 v4f; S still never
// touches global.

#define EPSV 1e-5f
constexpr int NN  = 512;
constexpr int JJ  = 48;
constexpr int EE  = NN * JJ;   // 24576 edges

// ---- workspace layout (bytes) -------------------------------------------
constexpr size_t WTOFFS[4] = {0, 33280, 66560, 99840};        // halfs, rows [o][CKP]
constexpr size_t ST_BYTE = 398336;
constexpr size_t DI_BYTE = 398464;
constexpr size_t H2T_BYTE  = 33554432;                        // h2T [c][EE] per pair
constexpr size_t H2T_PAIRB = 7372800;                         // bytes per pair slab
constexpr size_t W2H_BYTE  = 67108864;

typedef _Float16 f16_t;
typedef __attribute__((ext_vector_type(4))) _Float16 v4h;
typedef __attribute__((ext_vector_type(8))) _Float16 v8h;
typedef __attribute__((ext_vector_type(4))) float v4f;

// ---------------------------------------------------------------- k0
__global__ __launch_bounds__(256) void k0_prep(
    const float* __restrict__ w1, const float* __restrict__ b1,
    const void* __restrict__ nmask,
    const float* __restrict__ x0, const float* __restrict__ x1,
    const float* __restrict__ ks0, const float* __restrict__ ks1,
    const float* __restrict__ w2,
    const float* __restrict__ w3_00, const float* __restrict__ b3_00,
    const float* __restrict__ w3_01, const float* __restrict__ b3_01,
    const float* __restrict__ w3_10, const float* __restrict__ b3_10,
    const float* __restrict__ w3_11, const float* __restrict__ b3_11,
    float* __restrict__ dInv, float* __restrict__ out, float* __restrict__ stats,
    _Float16* __restrict__ WT, _Float16* __restrict__ w2h,
    _Float16* __restrict__ h2t0)
{
    const int t = threadIdx.x;
    if (blockIdx.x == 0) {
        const int p = t >> 6, lane = t & 63;
        const float w0 = w1[p*128 + lane],       b0 = b1[p*128 + lane];
        const float w1v = w1[p*128 + 64 + lane], b1v = b1[p*128 + 64 + lane];
        float sw = w0 + w1v, sb = b0 + b1v;
        float sww = w0*w0 + w1v*w1v, swb = w0*b0 + w1v*b1v, sbb = b0*b0 + b1v*b1v;
        for (int off = 32; off > 0; off >>= 1) {
            sw  += __shfl_down(sw, off);  sb  += __shfl_down(sb, off);
            sww += __shfl_down(sww, off); swb += __shfl_down(swb, off);
            sbb += __shfl_down(sbb, off);
        }
        if (lane == 0) {
            const float wbar = sw*(1.f/128.f), bbar = sb*(1.f/128.f);
            stats[p*8+0] = wbar; stats[p*8+1] = bbar;
            stats[p*8+2] = sww*(1.f/128.f) - wbar*wbar;
            stats[p*8+3] = swb*(1.f/128.f) - wbar*bbar;
            stats[p*8+4] = sbb*(1.f/128.f) - bbar*bbar;
        }
        return;
    }
    if (blockIdx.x == 1) {
        __shared__ int flag;
        if (t == 0) flag = 0;
        __syncthreads();
        const int* m32 = (const int*)nmask;
        int bad = 0;
        for (int i = t; i < EE/4; i += 256) if ((unsigned)m32[i] > 1u) bad = 1;
        if (bad) flag = 1;
        __syncthreads();
        const int useU8 = flag;
        if (t == 0) stats[30] = useU8 ? 1.f : 0.f;
        for (int n = t; n < NN; n += 256) {
            float s = 0.f;
            if (useU8) {
                const unsigned char* m8 = (const unsigned char*)nmask;
                for (int j = 0; j < JJ; ++j) s += m8[n*JJ + j] ? 1.f : 0.f;
            } else {
                for (int j = 0; j < JJ; ++j) s += m32[n*JJ + j] ? 1.f : 0.f;
            }
            dInv[n] = 1.f / s;
        }
        return;
    }
    if (blockIdx.x < 130) {              // self-interaction init
        const int gid = (blockIdx.x - 2) * 256 + t;
        const int d = gid & 3, o = (gid >> 2) & 15, n = gid >> 6;
        float acc = 0.f;
        if (d == 0) {
            #pragma unroll
            for (int i = 0; i < 16; ++i) acc += ks0[o*16+i] * x0[n*16+i];
        } else {
            const int u = d - 1;
            #pragma unroll
            for (int i = 0; i < 16; ++i) acc += ks1[o*16+i] * x1[(n*16+i)*3 + u];
        }
        out[gid] = acc;
        return;
    }
    if (blockIdx.x < 908) {              // WT: [o][CKP] fp16, zero-padded tail
        const int gid = (blockIdx.x - 130) * 256 + t;   // [0, 199168)
        if (gid >= 199168) return;
        int p, base;
        if      (gid < 33280)  { p = 0; base = 0; }
        else if (gid < 66560)  { p = 1; base = 33280; }
        else if (gid < 99840)  { p = 2; base = 66560; }
        else                   { p = 3; base = 99840; }
        const int KF = (p == 3) ? 48 : 16;
        const int CK = 129*KF, CKP = CK + 16;
        const int e = gid - base;
        const int o = e / CKP, ck = e - o*CKP;
        float v = 0.f;
        if (ck < CK) {
            const int c = ck / KF, k = ck - c*KF;
            const float* w3 = (p==0) ? w3_00 : (p==1) ? w3_01 : (p==2) ? w3_10 : w3_11;
            const float* b3 = (p==0) ? b3_00 : (p==1) ? b3_01 : (p==2) ? b3_10 : b3_11;
            v = (c < 128) ? w3[(size_t)c*(16*KF) + o*KF + k] : b3[o*KF + k];
        }
        WT[base + (size_t)o*CKP + ck] = (_Float16)v;
        return;
    }
    if (blockIdx.x < 1164) {
        // w2 transpose -> fp16: w2h[p][c][k] = w2[p][k][c]
        const int gid = (blockIdx.x - 908) * 256 + t;   // [0, 65536)
        const int p = gid >> 14, rem = gid & 16383;
        const int c = rem >> 7, k = rem & 127;
        w2h[gid] = (_Float16)w2[p*16384 + k*128 + c];
        return;
    }
    // h2T ones row (c=128, the b3 row) per pair
    const int gid = (blockIdx.x - 1164) * 256 + t;      // [0, 12288)
    const int p = gid / 3072, r8 = gid - p*3072;
    union { float4 f; _Float16 h[8]; } one;
    #pragma unroll
    for (int i = 0; i < 8; ++i) one.h[i] = (_Float16)1.f;
    *(float4*)(h2t0 + (size_t)p*(H2T_PAIRB/2) + (size_t)128*EE + r8*8) = one.f;
}

// ---------------------------------------------------------------- k1: radial MLP (MFMA) -> h2T
__global__ __launch_bounds__(256) void k1_mfma(
    const float* __restrict__ rel,
    const float* __restrict__ w1, const float* __restrict__ b1,
    const float* __restrict__ g1, const float* __restrict__ be1,
    const float* __restrict__ b2, const float* __restrict__ g2,
    const float* __restrict__ be2,
    const float* __restrict__ stats, char* __restrict__ ws)
{
    const int p  = blockIdx.y;
    const int e0 = blockIdx.x * 64;
    const int t  = threadIdx.x;
    const _Float16* __restrict__ w2h = (const _Float16*)(ws + W2H_BYTE) + (size_t)p*16384;
    _Float16* __restrict__ h2Tg = (_Float16*)(ws + H2T_BYTE + (size_t)p*H2T_PAIRB);

    __shared__ __align__(16) _Float16 w2L[128*136];
    __shared__ float pb[384];
    _Float16* h1T = w2L;                              // overlay after MFMA

    if (t < 128) {
        pb[t]       = b2[p*128 + t];
        pb[128 + t] = g2[p*128 + t];
        pb[256 + t] = be2[p*128 + t];
    }
    for (int i = t; i < 2048; i += 256) {
        const int c = i >> 4, off = (i & 15) * 8;
        *(float4*)(w2L + c*136 + off) = *(const float4*)(w2h + c*128 + off);
    }

    const int l = t & 63, wv = t >> 6;
    const int q = l >> 4, c16 = l & 15;
    const int m0 = wv * 16;

    const float d    = rel[e0 + m0 + c16];
    const float wbar = stats[p*8+0], bbar = stats[p*8+1];
    const float Cw = stats[p*8+2], Cwb = stats[p*8+3], Cb = stats[p*8+4];
    const float mu1 = fmaf(d, wbar, bbar);
    const float rs1 = rsqrtf(fmaf(d*d, Cw, fmaf(2.f*d, Cwb, Cb)) + EPSV);

    __syncthreads();

    v4f acc[8];
    #pragma unroll
    for (int nt = 0; nt < 8; ++nt) { acc[nt][0]=0.f; acc[nt][1]=0.f; acc[nt][2]=0.f; acc[nt][3]=0.f; }

    #pragma unroll
    for (int ks = 0; ks < 4; ++ks) {
        const int cb = p*128 + ks*32 + q*8;
        const float4 wA = *(const float4*)(w1 + cb),  wB = *(const float4*)(w1 + cb + 4);
        const float4 bA = *(const float4*)(b1 + cb),  bB = *(const float4*)(b1 + cb + 4);
        const float4 gA = *(const float4*)(g1 + cb),  gB = *(const float4*)(g1 + cb + 4);
        const float4 eA = *(const float4*)(be1 + cb), eB = *(const float4*)(be1 + cb + 4);
        const float wv8[8] = {wA.x,wA.y,wA.z,wA.w,wB.x,wB.y,wB.z,wB.w};
        const float bv8[8] = {bA.x,bA.y,bA.z,bA.w,bB.x,bB.y,bB.z,bB.w};
        const float gv8[8] = {gA.x,gA.y,gA.z,gA.w,gB.x,gB.y,gB.z,gB.w};
        const float ev8[8] = {eA.x,eA.y,eA.z,eA.w,eB.x,eB.y,eB.z,eB.w};
        v8h a;
        #pragma unroll
        for (int j = 0; j < 8; ++j) {
            const float y = fmaf((fmaf(d, wv8[j], bv8[j]) - mu1) * rs1, gv8[j], ev8[j]);
            a[j] = (_Float16)fmaxf(y, 0.f);
        }
        const int k0 = ks*32 + q*8;
        #pragma unroll
        for (int nt = 0; nt < 8; ++nt) {
            const v8h bf = *(const v8h*)(w2L + (nt*16 + c16)*136 + k0);
            acc[nt] = __builtin_amdgcn_mfma_f32_16x16x32_f16(a, bf, acc[nt], 0, 0, 0);
        }
    }
    __syncthreads();

    float bl[8], gl[8], bel[8];
    #pragma unroll
    for (int nt = 0; nt < 8; ++nt) {
        bl[nt]  = pb[nt*16 + c16];
        gl[nt]  = pb[128 + nt*16 + c16];
        bel[nt] = pb[256 + nt*16 + c16];
    }
    #pragma unroll
    for (int nt = 0; nt < 8; ++nt)
        #pragma unroll
        for (int r = 0; r < 4; ++r) acc[nt][r] += bl[nt];

    float muR[4], rsR[4];
    #pragma unroll
    for (int r = 0; r < 4; ++r) {
        float s = 0.f, qq = 0.f;
        #pragma unroll
        for (int nt = 0; nt < 8; ++nt) { const float v = acc[nt][r]; s += v; qq += v*v; }
        #pragma unroll
        for (int m = 1; m < 16; m <<= 1) { s += __shfl_xor(s, m); qq += __shfl_xor(qq, m); }
        muR[r] = s * (1.f/128.f);
        rsR[r] = rsqrtf(qq*(1.f/128.f) - muR[r]*muR[r] + EPSV);
    }
    #pragma unroll
    for (int nt = 0; nt < 8; ++nt) {
        union { uint2 uu; _Float16 h[4]; } pk;
        #pragma unroll
        for (int r = 0; r < 4; ++r)
            pk.h[r] = (_Float16)fmaxf(fmaf((acc[nt][r] - muR[r])*rsR[r], gl[nt], bel[nt]), 0.f);
        *(uint2*)(h1T + (nt*16 + c16)*72 + m0 + q*4) = pk.uu;
    }
    __syncthreads();

    for (int i = t; i < 1024; i += 256) {
        const int c = i >> 3, off = (i & 7) * 8;
        *(float4*)(h2Tg + (size_t)c*EE + e0 + off) = *(const float4*)(h1T + c*72 + off);
    }
}

// ---------------------------------------------------------------- k2c: fused, c-chunked
template<int DI, int DO>
__device__ __forceinline__ void k2c_dev(
    const int n, const float* __restrict__ xsrc,
    const int* __restrict__ nidx, const void* __restrict__ nmaskv,
    const float* __restrict__ basis, const _Float16* __restrict__ h2Tg,
    const float* __restrict__ stats, const _Float16* __restrict__ wt,
    const float* __restrict__ dInv, float* __restrict__ out, char* smem)
{
    constexpr int V  = 2*DI + 1;
    constexpr int U  = 2*DO + 1;
    constexpr int F  = 2*(DI < DO ? DI : DO) + 1;
    constexpr int KF = 16*F;
    constexpr int Q  = 16*U*F;
    constexpr int BP = U*V*F;
    constexpr int XW = 16*V;
    constexpr int CK  = 129*KF;
    constexpr int CKP = CK + 16;        // WT row stride (halfs)
    constexpr int NK  = CKP/32;         // total 32-half K-steps
    constexpr int MT  = Q/16;
    constexpr int CHALF = 48*KF;        // halfs per chunk per u-row (3 c-tiles)
    constexpr int SLP   = CHALF + 8;    // Sl row stride
    constexpr int CSTEP = CHALF/32;     // full-chunk K-steps
    constexpr int TTC   = (MT*3 + 3)/4; // frag regs per wave per chunk (<=7)
    constexpr int ZST   = 129*KF - 2*CHALF;  // chunk-2 zero-tail start (Sl idx)

    _Float16* EmT = (_Float16*)smem;                          // [Q][56]
    char* region2 = smem + Q*112;                             // 16128 B
    float* xg   = (float*)region2;                            // [48][XW]
    float* basL = xg + 48*XW;
    _Float16* h2L = (_Float16*)region2;                       // overlay [144][56]
    int2*  lut  = (int2*)(region2 + 16128);
    int*   idxL = (int*)(lut + Q);
    float* mjf  = (float*)(idxL + 48);
    _Float16* Sl = (_Float16*)(smem + Q*112 + 16128 + 1536);  // [4][SLP]
    float* red   = (float*)smem;                              // final overlay [4][16][16]

    const int t = threadIdx.x;
    const int wv = t >> 6, l = t & 63;
    const int q8 = l >> 4, l15 = l & 15;

    // h2T window prefetch -> registers: 129 rows x 6 segs x 8 halfs (uint4)
    uint4 h2r[4];
    int   h2i[4];
    #pragma unroll
    for (int uu = 0; uu < 4; ++uu) {
        const int idx = t + uu*256;
        h2i[uu] = (idx < 774) ? idx : -1;
        if (idx < 774) {
            const int r = idx / 6, s = idx - r*6;
            h2r[uu] = *(const uint4*)(h2Tg + (size_t)r*EE + n*48 + s*8);
        }
    }

    if (t < 48) {
        idxL[t] = nidx[n*JJ + t];
        const int useU8 = (stats[30] != 0.f);
        const int mv = useU8 ? (int)((const unsigned char*)nmaskv)[n*JJ + t]
                             : ((const int*)nmaskv)[n*JJ + t];
        mjf[t] = mv ? 1.f : 0.f;
    }
    if (t >= 64 && t < 64 + Q) {
        const int q2 = t - 64;
        const int u = q2 / KF, k = q2 - u*KF, i = k / F, f = k - i*F;
        lut[q2] = make_int2((u*V)*F + f, i*V);
    }
    __syncthreads();

    for (int e = t; e < 48*XW; e += 256) {
        const int j = e / XW, r = e - j*XW;
        xg[e] = xsrc[idxL[j]*XW + r];
    }
    for (int e = t; e < 48*BP; e += 256)
        basL[e] = basis[(size_t)n*48*BP + e];
    __syncthreads();

    // EmT[q][j] = mjf[j] * sum_v basis[j][(u*V+v)*F+f] * xg[j][i*V+v]
    for (int e = t; e < Q*48; e += 256) {
        const int q2 = e / 48, j = e - q2*48;
        const int2 lu = lut[q2];
        float a = 0.f;
        #pragma unroll
        for (int v = 0; v < V; ++v)
            a = fmaf(basL[j*BP + lu.x + v*F], xg[j*XW + lu.y + v], a);
        EmT[q2*56 + j] = (_Float16)(mjf[j] * a);
    }
    __syncthreads();   // xg/basL dead

    // spill h2 window -> h2L
    #pragma unroll
    for (int uu = 0; uu < 4; ++uu) {
        if (h2i[uu] >= 0) {
            const int r = h2i[uu] / 6, s = h2i[uu] - r*6;
            *(uint4*)(h2L + r*56 + s*8) = h2r[uu];
        }
    }
    for (int i = t; i < 15*7; i += 256) {
        const int r = 129 + i/7, s = i - (i/7)*7;
        *(uint4*)(h2L + r*56 + s*8) = make_uint4(0u,0u,0u,0u);
    }

    v4f acc2; acc2[0]=0.f; acc2[1]=0.f; acc2[2]=0.f; acc2[3]=0.f;
    const _Float16* wrow = wt + (size_t)l15*CKP;
    const _Float16* srow = Sl + (l15 & 3)*SLP;

    #pragma unroll
    for (int chunk = 0; chunk < 3; ++chunk) {
        __syncthreads();   // Sl safe to overwrite (prev phase C done); also h2L ready (chunk 0)

        if (chunk == 2) {  // zero the c>128 tail of Sl before phase C reads it
            for (int i = t; i < 4*(CHALF - ZST)/8; i += 256) {
                const int u = i / ((CHALF - ZST)/8), s = i - u*((CHALF - ZST)/8);
                *(uint4*)(Sl + u*SLP + ZST + s*8) = make_uint4(0u,0u,0u,0u);
            }
        }

        // phase B chunk: S fragments (registers)
        v4f dreg[TTC];
        #pragma unroll
        for (int i = 0; i < TTC; ++i) {
            const int tc = wv + i*4;
            v4f acc; acc[0]=0.f; acc[1]=0.f; acc[2]=0.f; acc[3]=0.f;
            if (tc < MT*3) {
                const int mt = tc / 3, nt = chunk*3 + (tc - mt*3);
                #pragma unroll
                for (int ks = 0; ks < 3; ++ks) {
                    const v4h a = *(const v4h*)(EmT + (mt*16 + l15)*56 + ks*16 + q8*4);
                    const v4h b = *(const v4h*)(h2L + (nt*16 + l15)*56 + ks*16 + q8*4);
                    acc = __builtin_amdgcn_mfma_f32_16x16x16f16(a, b, acc, 0, 0, 0);
                }
            }
            dreg[i] = acc;
        }
        // store fragments -> Sl (chunk-local ck index)
        #pragma unroll
        for (int i = 0; i < TTC; ++i) {
            const int tc = wv + i*4;
            if (tc < MT*3) {
                const int mt = tc / 3, nt = chunk*3 + (tc - mt*3);
                const int c = nt*16 + l15;
                if (c <= 128) {
                    const int q0 = mt*16 + q8*4;
                    const int u = q0 / KF, k0 = q0 - u*KF;
                    union { uint2 uu; _Float16 h[4]; } pk;
                    #pragma unroll
                    for (int r = 0; r < 4; ++r) pk.h[r] = (_Float16)dreg[i][r];
                    *(uint2*)(Sl + u*SLP + c*KF + k0 - chunk*CHALF) = pk.uu;
                }
            }
        }
        __syncthreads();

        // phase C chunk: accumulate D2[o][u] over this chunk's K-range
        const int base  = chunk*CSTEP;
        const int steps = (chunk < 2) ? CSTEP : (NK - 2*CSTEP);
        const int kc    = (steps + 3) >> 2;
        const int s_lo  = wv*kc;
        const int s_hi  = (s_lo + kc < steps) ? (s_lo + kc) : steps;
        #pragma unroll 4
        for (int s = s_lo; s < s_hi; ++s) {
            const int ck = (base + s)*32;
            const v8h a = *(const v8h*)(wrow + ck + q8*8);
            const v8h b = *(const v8h*)(srow + (ck - chunk*CHALF) + q8*8);
            acc2 = __builtin_amdgcn_mfma_f32_16x16x32_f16(a, b, acc2, 0, 0, 0);
        }
    }
    __syncthreads();   // all Sl/EmT reads done; red overlay safe

    #pragma unroll
    for (int r = 0; r < 4; ++r)
        red[(wv*16 + q8*4 + r)*16 + l15] = acc2[r];   // red[wv][o][u]
    __syncthreads();

    if (t < 16*U) {
        const int o = t & 15, u = t >> 4;
        const float v = red[(0*16 + o)*16 + u] + red[(1*16 + o)*16 + u]
                      + red[(2*16 + o)*16 + u] + red[(3*16 + o)*16 + u];
        atomicAdd(out + (size_t)(n*16 + o)*4 + (DO ? 1 + u : 0), v * dInv[n]);
    }
}

__global__ __launch_bounds__(256, 3) void k2c_all(
    const float* __restrict__ x0, const float* __restrict__ x1,
    const int* __restrict__ nidx, const void* __restrict__ nmask,
    const float* __restrict__ b00, const float* __restrict__ b01,
    const float* __restrict__ b10, const float* __restrict__ b11,
    const float* __restrict__ stats, const float* __restrict__ dInv,
    char* __restrict__ ws, float* __restrict__ out)
{
    __shared__ __align__(16) char smem[52352];   // pair3: 16128+16128+1536+4*2312*2
    const int pair = blockIdx.x >> 9, n = blockIdx.x & 511;
    const char* h2t = ws + H2T_BYTE;
    const _Float16* WT = (const _Float16*)ws;
    switch (pair) {
    case 0: k2c_dev<0,0>(n, x0, nidx, nmask, b00, (const _Float16*)(h2t + 0*H2T_PAIRB), stats, WT + WTOFFS[0], dInv, out, smem); break;
    case 1: k2c_dev<0,1>(n, x0, nidx, nmask, b01, (const _Float16*)(h2t + 1*H2T_PAIRB), stats, WT + WTOFFS[1], dInv, out, smem); break;
    case 2: k2c_dev<1,0>(n, x1, nidx, nmask, b10, (const _Float16*)(h2t + 2*H2T_PAIRB), stats, WT + WTOFFS[2], dInv, out, smem); break;
    default: k2c_dev<1,1>(n, x1, nidx, nmask, b11, (const _Float16*)(h2t + 3*H2T_PAIRB), stats, WT + WTOFFS[3], dInv, out, smem); break;
    }
}

// ---------------------------------------------------------------- launch
extern "C" void kernel_launch(void* const* d_in, const int* in_sizes, int n_in,
                              void* d_out, int out_size, void* d_ws, size_t ws_size,
                              hipStream_t stream)
{
    const float* x0    = (const float*)d_in[0];
    const float* x1    = (const float*)d_in[1];
    const float* rel   = (const float*)d_in[2];
    const int*   nidx  = (const int*)d_in[3];
    const void*  nmask = d_in[4];
    const float* basis[4] = {(const float*)d_in[5], (const float*)d_in[6],
                             (const float*)d_in[7], (const float*)d_in[8]};
    const float* w1  = (const float*)d_in[9];
    const float* b1  = (const float*)d_in[10];
    const float* g1  = (const float*)d_in[11];
    const float* be1 = (const float*)d_in[12];
    const float* w2  = (const float*)d_in[13];
    const float* b2  = (const float*)d_in[14];
    const float* g2  = (const float*)d_in[15];
    const float* be2 = (const float*)d_in[16];
    const float* w3a[4] = {(const float*)d_in[17], (const float*)d_in[19],
                           (const float*)d_in[21], (const float*)d_in[23]};
    const float* b3a[4] = {(const float*)d_in[18], (const float*)d_in[20],
                           (const float*)d_in[22], (const float*)d_in[24]};
    const float* ks0 = (const float*)d_in[25];
    const float* ks1 = (const float*)d_in[26];
    float* out = (float*)d_out;

    char*      ws    = (char*)d_ws;
    _Float16*  WT    = (_Float16*)ws;
    float*     stats = (float*)(ws + ST_BYTE);
    float*     dInv  = (float*)(ws + DI_BYTE);
    _Float16*  w2h   = (_Float16*)(ws + W2H_BYTE);
    _Float16*  h2t0  = (_Float16*)(ws + H2T_BYTE);

    k0_prep<<<1212, 256, 0, stream>>>(w1, b1, nmask, x0, x1, ks0, ks1, w2,
                                      w3a[0], b3a[0], w3a[1], b3a[1],
                                      w3a[2], b3a[2], w3a[3], b3a[3],
                                      dInv, out, stats, WT, w2h, h2t0);

    k1_mfma<<<dim3(384, 4), 256, 0, stream>>>(rel, w1, b1, g1, be1, b2, g2, be2, stats, ws);

    k2c_all<<<2048, 256, 0, stream>>>(x0, x1, nidx, nmask,
                                      basis[0], basis[1], basis[2], basis[3],
                                      stats, dInv, ws, out);
}